// Round 4
// baseline (55836.884 us; speedup 1.0000x reference)
//
#include <hip/hip_runtime.h>
#include <hip/hip_bf16.h>

// DecoderRNN v4: 3-layer GRU, B=512, S=200, H=1024, V=100, teacher-forced.
// v3 structure (persistent weights in VGPRs, barrier-free K-loop, diagonal
// pipeline) with ALL partial-sum exchanges in fp32 (v3's bf16 partial spills
// caused absmax 0.118 > 0.059; v2's all-fp32 gate math gave 0.0156).
// Roles per diagonal d (205 launches, 328 blocks):
//   C0:  h0(d)   = GRU(gi0 table/gprec gather, gh0 = h0(d-1)@whh0)
//   GI1: gi1(d-1)= h0(d-1)@wih1 -> fp32 per-kh arena, in-block combine -> gic
//   C1:  h1(d-2) = GRU(gic1(d-2),  gh1 = h1(d-3)@whh1)
//   GI2: gi2(d-3)= h1(d-3)@wih2 -> gic
//   C2:  h2(d-4) = GRU(gic2(d-4),  gh2 = h2(d-5)@whh2)
//   OUT: logits(d-5) = h2(d-5)@owT + logit_de
// Every role: M512(x2 blocks) x N(3x32|32x4) x K1024 bf16 GEMM; wave =
// (kh 512, nh 16, all gates); weight frags pinned in 192 VGPRs; A streamed
// via per-wave-private double-buffered 8KB LDS chunks gated by own-wave
// s_waitcnt vmcnt(N); ONE __syncthreads per block before the fp32 combine.

typedef __hip_bfloat16 bf16;
typedef __attribute__((ext_vector_type(8))) short short8;
typedef __attribute__((ext_vector_type(4))) float f32x4;

#define B_ 512
#define S_ 200
#define H_ 1024
#define V_ 100

__device__ __forceinline__ float bf2f(bf16 x) { return __bfloat162float(x); }

// ---- workspace layout (bytes); total ~135.4 MB ----
#define OFF_GPREC 0u           //  6,291,456  fp32 [512][3072]
#define OFF_TABLE 6291456u     //  1,228,800  fp32 [100][3072]
#define OFF_LOGITDE 7520256u   //    204,800  fp32 [512][100]
#define OFF_BIAS4 7725056u     //     49,152  fp32 [3][4][1024]
#define OFF_WWHH0 7774208u     //  6,291,456  bf16 [3072][1024]
#define OFF_WWIH1 14065664u
#define OFF_WWHH1 20357120u
#define OFF_WWIH2 26648576u
#define OFF_WWHH2 32940032u
#define OFF_OWTV 39231488u     //    262,144  bf16 [128][1024]
#define OFF_HBUF 39493632u     //  6,291,456  bf16 [2 par][3][512][1024]
#define OFF_GIC 45785088u      // 25,165,824  fp32 [2 rr][2 par][3][512][1024]
#define OFF_ARENA 70950912u    // 64,487,424  fp32 328 blk x 49152
#define OFF_DE (OFF_ARENA)     // transient (precompute only, 2 MB)
#define OFF_HINIT (OFF_ARENA + 2097152u)  // transient, 2 MB

// Stage one A-chunk (m16 x k256 = 8KB) into a wave-private LDS buffer.
// 16B granules XOR-swizzled by (row&7) on the SOURCE side so frag reads
// (ds_read_b128) are conflict-free while the DMA dest stays base+lane*16.
__device__ __forceinline__ void stage_chunk(char* buf, const bf16* __restrict__ A,
                                            int mbase, int kh, int ci, int lane) {
  const int mt = ci >> 1, kc = ci & 1;
#pragma unroll
  for (int i = 0; i < 8; ++i) {
    const int rl = 2 * i + (lane >> 5);                 // row within chunk
    const int row = mbase + mt * 16 + rl;
    const int gsel = (lane & 31) ^ (rl & 7);
    const char* gp = (const char*)A + row * 2048 + kh * 1024 + kc * 512 + gsel * 16;
    __builtin_amdgcn_global_load_lds(
        (const __attribute__((address_space(1))) void*)gp,
        (__attribute__((address_space(3))) void*)(buf + i * 1024), 16, 0, 0);
  }
}

// Phase-1 GEMM: P[kh][g][mloc 0..255][nh*16+col] (fp32) =
//   sum_{k in kh*512+[0,512)} A[mbase+mloc][k] * W[g*1024 + nbt+nh*16+col][k]
template <int NG>
__device__ __forceinline__ void phase1(char* smem, int tid,
    const bf16* __restrict__ A, int mbase, const bf16* __restrict__ W,
    int nbt, float* __restrict__ pbase, int sKH, int sG) {
  const int lane = tid & 63;
  const int w = tid >> 6;
  const int kh = w & 1, nh = w >> 1;
  const int col = lane & 15, q = lane >> 4;
  char* mybuf = smem + w * 16384;

  // pin weight fragments in VGPRs (one-time per launch, from L2/L3)
  short8 wf[NG][16];
  const bf16* wp = W + (size_t)(nbt + nh * 16 + col) * 1024 + kh * 512 + q * 8;
#pragma unroll
  for (int g = 0; g < NG; ++g)
#pragma unroll
    for (int kk = 0; kk < 16; ++kk)
      wf[g][kk] = *(const short8*)(wp + g * 1048576 + kk * 32);

  f32x4 acc[NG];
#pragma unroll
  for (int g = 0; g < NG; ++g)
#pragma unroll
    for (int r = 0; r < 4; ++r) acc[g][r] = 0.f;

  stage_chunk(mybuf, A, mbase, kh, 0, lane);
  __builtin_amdgcn_s_waitcnt(0x0f70);  // vmcnt(0): wf + chunk0 resident

  for (int ci = 0; ci < 32; ++ci) {
    if (ci + 1 < 32) {
      stage_chunk(mybuf + ((ci + 1) & 1) * 8192, A, mbase, kh, ci + 1, lane);
      __builtin_amdgcn_s_waitcnt(0x0f78);  // vmcnt(8): chunk ci resident
    } else {
      __builtin_amdgcn_s_waitcnt(0x0f70);
    }
    const char* buf = mybuf + (ci & 1) * 8192;
    const int kc = ci & 1;
#pragma unroll
    for (int j = 0; j < 8; ++j) {
      short8 af = *(const short8*)(buf + col * 512 +
                                   (((j * 4 + q) ^ (col & 7)) * 16));
#pragma unroll
      for (int g = 0; g < NG; ++g)
        acc[g] = __builtin_amdgcn_mfma_f32_16x16x32_bf16(af, wf[g][kc * 8 + j],
                                                         acc[g], 0, 0, 0);
    }
    if (kc) {  // m-tile complete -> spill fp32 partials
      const int mt = ci >> 1;
#pragma unroll
      for (int g = 0; g < NG; ++g)
#pragma unroll
        for (int r = 0; r < 4; ++r) {
          const int mloc = mt * 16 + q * 4 + r;  // C/D: col=lane&15,row=q*4+r
          pbase[kh * sKH + g * sG + mloc * 32 + nh * 16 + col] = acc[g][r];
          acc[g][r] = 0.f;
        }
    }
  }
}

// ---------------------------------------------------------------------------
__global__ __launch_bounds__(256, 2) void diag_kernel(int d,
    const int* __restrict__ inputs, char* __restrict__ ws,
    float* __restrict__ out) {
  __shared__ char smem[65536];
  const int bi = blockIdx.x, tid = threadIdx.x;
  const int par = d & 1, rpar = par ^ 1;
  const bf16* hbuf = (const bf16*)(ws + OFF_HBUF);
  bf16* hbufw = (bf16*)(ws + OFF_HBUF);
  const float* bias4 = (const float*)(ws + OFF_BIAS4);
  float* arena = (float*)(ws + OFF_ARENA);

  if (bi < 192) {  // --- C roles: gh GEMM + fp32 combine + GRU ---
    const int layer = bi >> 6, sub = bi & 63;
    const int nt = sub >> 1, mh = sub & 1, mbase = mh * 256;
    const int t = d - 2 * layer;
    if (t < 0 || t >= S_) return;
    const bf16* A = hbuf + (rpar * 3 + layer) * 524288;  // = h_l(t-1)
    const bf16* W = (const bf16*)(ws + (layer == 0 ? OFF_WWHH0
                                  : layer == 1 ? OFF_WWHH1 : OFF_WWHH2));
    float* cp = arena + (size_t)bi * 49152;
    phase1<3>(smem, tid, A, mbase, W, nt * 32, cp, 24576, 8192);
    __syncthreads();

    bf16* hout = hbufw + (par * 3 + layer) * 524288;
    const float* b4 = bias4 + layer * 4096;
    const float* table = (const float*)(ws + OFF_TABLE);
    const float* gprec = (const float*)(ws + OFF_GPREC);
    const float* gcb = (const float*)(ws + OFF_GIC) +
                       (size_t)((layer - 1) * 2 + rpar) * 3 * 524288;
    for (int e = 0; e < 32; ++e) {
      const int idx = tid + e * 256;     // 256 m x 32 n
      const int nl = idx & 31, ml = idx >> 5;
      const int b = mbase + ml, n = nt * 32 + nl;
      float ghr = cp[idx] + cp[24576 + idx];
      float ghz = cp[8192 + idx] + cp[32768 + idx];
      float ghn = cp[16384 + idx] + cp[40960 + idx];
      float rt, zt, npre, hn;
      if (layer == 0) {
        const int tok = (t == 0) ? 1 : inputs[b * S_ + (t - 1)];
        const float* tb = table + tok * 3072;
        const float* gp = gprec + b * 3072;
        rt = ghr + tb[n] + gp[n] + b4[n];
        zt = ghz + tb[1024 + n] + gp[1024 + n] + b4[1024 + n];
        npre = tb[2048 + n] + gp[2048 + n];
        hn = ghn + b4[3072 + n];
      } else {
        rt = ghr + gcb[b * 1024 + n] + b4[n];
        zt = ghz + gcb[524288 + b * 1024 + n] + b4[1024 + n];
        npre = gcb[1048576 + b * 1024 + n] + b4[2048 + n];
        hn = ghn + b4[3072 + n];
      }
      float r = 1.f / (1.f + __expf(-rt));
      float z = 1.f / (1.f + __expf(-zt));
      float nn = npre + r * hn;
      float e2 = __expf(2.f * nn);
      float th = 1.f - 2.f / (e2 + 1.f);  // tanh, inf-safe
      float hp = bf2f(A[b * 1024 + n]);
      hout[b * 1024 + n] = __float2bfloat16((1.f - z) * th + z * hp);
    }
  } else if (bi < 320) {  // --- GI roles: gi GEMM, fp32 combine -> gic ---
    const int rr = (bi - 192) >> 6, sub = (bi - 192) & 63;
    const int nt = sub >> 1, mh = sub & 1, mbase = mh * 256;
    const int tg = d - 1 - 2 * rr;
    if (tg < 0 || tg >= S_) return;
    const bf16* A = hbuf + (rpar * 3 + rr) * 524288;  // h0(d-1) | h1(d-3)
    const bf16* W = (const bf16*)(ws + (rr == 0 ? OFF_WWIH1 : OFF_WWIH2));
    float* ap = arena + (size_t)bi * 49152;
    phase1<3>(smem, tid, A, mbase, W, nt * 32, ap, 24576, 8192);
    __syncthreads();
    float* gc = (float*)(ws + OFF_GIC) + (size_t)(rr * 2 + par) * 3 * 524288;
    for (int e = 0; e < 96; ++e) {
      const int idx = tid + e * 256;     // [g][256 m][32 n]
      const int g = idx >> 13, rem = idx & 8191;
      const int ml = rem >> 5, nl = rem & 31;
      gc[g * 524288 + (mbase + ml) * 1024 + nt * 32 + nl] =
          ap[idx] + ap[24576 + idx];
    }
  } else {  // --- OUT role ---
    const int sub = bi - 320;
    const int nt = sub >> 1, mh = sub & 1, mbase = mh * 256;
    const int t = d - 5;
    if (t < 0 || t >= S_) return;
    const bf16* A = hbuf + (rpar * 3 + 2) * 524288;  // h2(t)
    const bf16* W = (const bf16*)(ws + OFF_OWTV);
    float* op = arena + (size_t)bi * 49152;
    phase1<1>(smem, tid, A, mbase, W, nt * 32, op, 8192, 0);
    __syncthreads();
    const float* logitde = (const float*)(ws + OFF_LOGITDE);
    for (int e = 0; e < 32; ++e) {
      const int idx = tid + e * 256;
      const int nl = idx & 31, ml = idx >> 5;
      const int b = mbase + ml, v = nt * 32 + nl;
      if (v < V_) {
        float s = op[idx] + op[8192 + idx];
        out[(b * S_ + t) * V_ + v] = s + logitde[b * V_ + v];
      }
    }
  }
}

// ---------------------------------------------------------------------------
// fp32 precompute GEMM: C[m][n] = A[m]·W[n, woff:woff+K] + bias[n]
__global__ __launch_bounds__(256) void pgemm(
    const float* __restrict__ A, int lda, const float* __restrict__ W, int ldw,
    int woff, const float* __restrict__ bias, float* __restrict__ C,
    int M, int N, int K) {
  __shared__ float As[64][33];
  __shared__ float Ws[64][33];
  const int tid = threadIdx.x;
  const int tx = tid & 15, ty = tid >> 4;
  const int mb = blockIdx.x * 64, nb = blockIdx.y * 64;
  float acc[4][4];
#pragma unroll
  for (int i = 0; i < 4; ++i)
#pragma unroll
    for (int j = 0; j < 4; ++j) acc[i][j] = 0.f;
  for (int k0 = 0; k0 < K; k0 += 32) {
#pragma unroll
    for (int s = 0; s < 8; ++s) {
      int idx = s * 256 + tid;
      int r = idx >> 5, c = idx & 31;
      int m = mb + r;
      As[r][c] = (m < M) ? A[m * lda + k0 + c] : 0.f;
      int n = nb + r;
      Ws[r][c] = (n < N) ? W[n * ldw + woff + k0 + c] : 0.f;
    }
    __syncthreads();
#pragma unroll 8
    for (int kk = 0; kk < 32; ++kk) {
      float a[4], ww[4];
#pragma unroll
      for (int i = 0; i < 4; ++i) a[i] = As[ty * 4 + i][kk];
#pragma unroll
      for (int j = 0; j < 4; ++j) ww[j] = Ws[tx * 4 + j][kk];
#pragma unroll
      for (int i = 0; i < 4; ++i)
#pragma unroll
        for (int j = 0; j < 4; ++j) acc[i][j] += a[i] * ww[j];
    }
    __syncthreads();
  }
#pragma unroll
  for (int i = 0; i < 4; ++i) {
    int m = mb + ty * 4 + i;
    if (m >= M) continue;
#pragma unroll
    for (int j = 0; j < 4; ++j) {
      int n = nb + tx * 4 + j;
      if (n < N) C[m * N + n] = acc[i][j] + (bias ? bias[n] : 0.f);
    }
  }
}

// --------------------------- small pack kernels ----------------------------
__global__ void k_de(const float* __restrict__ z, const float* __restrict__ c,
                     float* __restrict__ de) {
  int i = blockIdx.x * 256 + threadIdx.x;
  int b = i >> 10, q = i & 1023;
  de[i] = (q < 512) ? z[b * 512 + q] : c[b * 512 + (q - 512)];
}

__global__ void k_cast(const float* __restrict__ s, bf16* __restrict__ dst,
                       int n) {
  int i = blockIdx.x * 256 + threadIdx.x;
  if (i < n) dst[i] = __float2bfloat16(s[i]);
}

__global__ void k_owt(const float* __restrict__ out_w, bf16* __restrict__ o) {
  int i = blockIdx.x * 256 + threadIdx.x;
  if (i >= 128 * H_) return;
  int v = i >> 10, k = i & 1023;
  o[i] = __float2bfloat16((v < V_) ? out_w[v * 2048 + k] : 0.f);
}

__global__ void k_bias4(const float* __restrict__ bih,
                        const float* __restrict__ bhh, float* __restrict__ dst,
                        int l0) {
  int n = blockIdx.x * 256 + threadIdx.x;
  if (n >= 1024) return;
  dst[n] = l0 ? bhh[n] : bih[n] + bhh[n];
  dst[1024 + n] = l0 ? bhh[1024 + n] : bih[1024 + n] + bhh[1024 + n];
  dst[2048 + n] = l0 ? 0.f : bih[2048 + n];
  dst[3072 + n] = bhh[2048 + n];
}

__global__ void k_hinit(const float* __restrict__ hinit, bf16* __restrict__ hb) {
  int i = blockIdx.x * 256 + threadIdx.x;  // 524288
  bf16 v = __float2bfloat16(hinit[i]);
  hb[3 * 524288 + i] = v;      // parity-1, layer 0
  hb[4 * 524288 + i] = v;      // parity-1, layer 1
  hb[5 * 524288 + i] = v;      // parity-1, layer 2
}

// ---------------------------------------------------------------------------
extern "C" void kernel_launch(void* const* d_in, const int* in_sizes, int n_in,
                              void* d_out, int out_size, void* d_ws,
                              size_t ws_size, hipStream_t stream) {
  const int* inputs = (const int*)d_in[0];
  const float* z = (const float*)d_in[1];
  const float* cond = (const float*)d_in[2];
  const float* emb = (const float*)d_in[4];
  const float* i2h_w = (const float*)d_in[5];
  const float* i2h_b = (const float*)d_in[6];
  const float* out_w = (const float*)d_in[7];
  const float* out_b = (const float*)d_in[8];
  const float* wih0 = (const float*)d_in[9];
  const float* whh0 = (const float*)d_in[10];
  const float* bih0 = (const float*)d_in[11];
  const float* bhh0 = (const float*)d_in[12];
  const float* wih1 = (const float*)d_in[13];
  const float* whh1 = (const float*)d_in[14];
  const float* bih1 = (const float*)d_in[15];
  const float* bhh1 = (const float*)d_in[16];
  const float* wih2 = (const float*)d_in[17];
  const float* whh2 = (const float*)d_in[18];
  const float* bih2 = (const float*)d_in[19];
  const float* bhh2 = (const float*)d_in[20];
  float* out = (float*)d_out;

  char* p = (char*)d_ws;
  float* de = (float*)(p + OFF_DE);          // transient (arena overlap)
  float* hinit = (float*)(p + OFF_HINIT);    // transient (arena overlap)
  float* gprec0 = (float*)(p + OFF_GPREC);
  float* table = (float*)(p + OFF_TABLE);
  float* logitde = (float*)(p + OFF_LOGITDE);
  float* bias4 = (float*)(p + OFF_BIAS4);

  // ---- one-time precompute ----
  k_de<<<2048, 256, 0, stream>>>(z, cond, de);
  pgemm<<<dim3(8, 48), 256, 0, stream>>>(de, 1024, wih0, 1536, 512, bih0,
                                         gprec0, 512, 3072, 1024);
  pgemm<<<dim3(2, 48), 256, 0, stream>>>(emb, 512, wih0, 1536, 0, nullptr,
                                         table, 100, 3072, 512);
  pgemm<<<dim3(8, 16), 256, 0, stream>>>(de, 1024, i2h_w, 1024, 0, i2h_b,
                                         hinit, 512, 1024, 1024);
  pgemm<<<dim3(8, 2), 256, 0, stream>>>(de, 1024, out_w, 2048, 1024, out_b,
                                        logitde, 512, 100, 1024);
  k_bias4<<<4, 256, 0, stream>>>(bhh0, bhh0, bias4, 1);
  k_bias4<<<4, 256, 0, stream>>>(bih1, bhh1, bias4 + 4096, 0);
  k_bias4<<<4, 256, 0, stream>>>(bih2, bhh2, bias4 + 8192, 0);
  k_cast<<<12288, 256, 0, stream>>>(whh0, (bf16*)(p + OFF_WWHH0), 3145728);
  k_cast<<<12288, 256, 0, stream>>>(wih1, (bf16*)(p + OFF_WWIH1), 3145728);
  k_cast<<<12288, 256, 0, stream>>>(whh1, (bf16*)(p + OFF_WWHH1), 3145728);
  k_cast<<<12288, 256, 0, stream>>>(wih2, (bf16*)(p + OFF_WWIH2), 3145728);
  k_cast<<<12288, 256, 0, stream>>>(whh2, (bf16*)(p + OFF_WWHH2), 3145728);
  k_owt<<<512, 256, 0, stream>>>(out_w, (bf16*)(p + OFF_OWTV));
  k_hinit<<<2048, 256, 0, stream>>>(hinit, (bf16*)(p + OFF_HBUF));

  // ---- diagonal-pipelined scan: d = 0 .. 204 ----
  for (int d = 0; d < S_ + 5; ++d) {
    diag_kernel<<<328, 256, 0, stream>>>(d, inputs, p, out);
  }
}